// Round 1
// baseline (370.557 us; speedup 1.0000x reference)
//
#include <hip/hip_runtime.h>
#include <hip/hip_cooperative_groups.h>

namespace cg = cooperative_groups;

#define N_NODES 3072
#define IN_DIM 512
#define OUT_DIM 64
#define HEADS 8
#define NEG_SLOPE 0.2f
#define MAX_E 128            // Poisson(~31) edges/row; 128 is >17 sigma
#define NBLK 768             // == proj tile count; 3 blocks/CU on 256 CUs

typedef __attribute__((ext_vector_type(8))) short bf16x8;
typedef __attribute__((ext_vector_type(4))) float f32x4;

#define XFRAG_TILES (N_NODES / 16)     // 192 row-tiles
#define KTILES (IN_DIM / 32)           // 16 k-tiles
#define XFRAG_THREADS (XFRAG_TILES * KTILES * 64)   // 196608 == NBLK*256
#define WFRAG_THREADS (HEADS * KTILES * 4 * 64)     // 32768

__device__ inline unsigned short f2bf(float f) {   // RNE float->bf16
    union { float f; unsigned u; } v; v.f = f;
    unsigned r = (v.u + 0x7FFF + ((v.u >> 16) & 1)) >> 16;
    return (unsigned short)r;
}

// Single cooperative kernel, 3 phases separated by grid.sync():
//   A: build bf16 fragment copies of x and W (exactly 1 xfrag elem/thread).
//   B: h = x @ W per head via direct-fragment MFMA; write bf16 node-major hb
//      + fp32 f_src/f_dst. One (rt-pair, head) tile per block (768 tiles).
//   C: per-row edge compaction + softmax + gather-aggregate, 4 rows/block.
// __launch_bounds__(256,3): 3 blocks/CU -> 768 blocks co-resident (coop-safe),
// VGPR cap ~170 (kt-loop unroll capped at 4 to avoid spill under the cap).
__global__ __launch_bounds__(256, 3) void gat_fused(
    const float* __restrict__ x, const float* __restrict__ adj,
    const float* __restrict__ W, const float* __restrict__ a_src,
    const float* __restrict__ a_dst,
    short* __restrict__ xfrag, short* __restrict__ wfrag,
    unsigned short* __restrict__ hb, float* __restrict__ fsrc,
    float* __restrict__ fdst, float* __restrict__ out) {
    __shared__ float hs[32][OUT_DIM + 1];   // phase B epilogue tile
    __shared__ int s_idx[MAX_E];            // phase C
    __shared__ float s_p[HEADS][MAX_E];     // phase C
    __shared__ int s_cnt;                   // phase C

    const int t = threadIdx.x;
    const int b = blockIdx.x;
    const int lane = t & 63;
    const int w = t >> 6;

    // ---------------- Phase A: fragment prep ----------------
    {
        const int tid = b * 256 + t;        // 0..196607, == XFRAG_THREADS
        {
            // xfrag[rt][kt][lane][8]: lane l holds x[rt*16+(l&15)][kt*32+(l>>4)*8+j]
            const int l = tid & 63;
            const int kt = (tid >> 6) & (KTILES - 1);
            const int rt = tid >> 10;
            const int m = rt * 16 + (l & 15);
            const int k0 = kt * 32 + (l >> 4) * 8;
            const float4* xp = (const float4*)(x + (size_t)m * IN_DIM + k0);
            float4 v0 = xp[0], v1 = xp[1];
            bf16x8 r;
            r[0] = (short)f2bf(v0.x); r[1] = (short)f2bf(v0.y);
            r[2] = (short)f2bf(v0.z); r[3] = (short)f2bf(v0.w);
            r[4] = (short)f2bf(v1.x); r[5] = (short)f2bf(v1.y);
            r[6] = (short)f2bf(v1.z); r[7] = (short)f2bf(v1.w);
            ((bf16x8*)xfrag)[tid] = r;
        }
        if (tid < WFRAG_THREADS) {
            // wfrag[head][kt][c][lane][8]: lane l holds W[head][kt*32+(l>>4)*8+j][c*16+(l&15)]
            const int l = tid & 63;
            const int c = (tid >> 6) & 3;
            const int kt = (tid >> 8) & (KTILES - 1);
            const int head = tid >> 12;
            const int n = c * 16 + (l & 15);
            const int k0 = kt * 32 + (l >> 4) * 8;
            const float* wp = W + ((size_t)head * IN_DIM + k0) * OUT_DIM + n;
            bf16x8 r;
#pragma unroll
            for (int j = 0; j < 8; ++j) r[j] = (short)f2bf(wp[(size_t)j * OUT_DIM]);
            ((bf16x8*)wfrag)[tid] = r;
        }
    }
    __threadfence();
    cg::this_grid().sync();

    // ---------------- Phase B: per-head projection ----------------
    {
        const int head = b / 96;            // 8 heads x 96 row-pair tiles
        const int rtp = b % 96;
        const int m0 = rtp * 32;
        const int rt0 = rtp * 2;

        const bf16x8* xa = (const bf16x8*)xfrag + (size_t)rt0 * 16 * 64 + lane;
        const bf16x8* wb = (const bf16x8*)wfrag + ((size_t)head * KTILES * 4 + w) * 64 + lane;

        f32x4 acc0 = {0.f, 0.f, 0.f, 0.f};
        f32x4 acc1 = {0.f, 0.f, 0.f, 0.f};
#pragma unroll 4
        for (int kt = 0; kt < KTILES; ++kt) {
            bf16x8 a0 = xa[kt * 64];            // rows m0..m0+15
            bf16x8 a1 = xa[(16 + kt) * 64];     // rows m0+16..m0+31
            bf16x8 bv = wb[kt * 4 * 64];        // cols w*16..w*16+15
            acc0 = __builtin_amdgcn_mfma_f32_16x16x32_bf16(a0, bv, acc0, 0, 0, 0);
            acc1 = __builtin_amdgcn_mfma_f32_16x16x32_bf16(a1, bv, acc1, 0, 0, 0);
        }

        // D mapping: col=lane&15 (within tile), row=(lane>>4)*4+i
        const int col = w * 16 + (lane & 15);
        const int r0 = (lane >> 4) * 4;
        unsigned short* hp = hb + (size_t)m0 * (HEADS * OUT_DIM) + head * OUT_DIM + col;
#pragma unroll
        for (int i2 = 0; i2 < 4; ++i2) {
            hs[r0 + i2][col] = acc0[i2];
            hs[r0 + 16 + i2][col] = acc1[i2];
            hp[(size_t)(r0 + i2) * (HEADS * OUT_DIM)] = f2bf(acc0[i2]);
            hp[(size_t)(r0 + 16 + i2) * (HEADS * OUT_DIM)] = f2bf(acc1[i2]);
        }
        __syncthreads();

        // f-pass: threads 0..127 -> f_src, 128..255 -> f_dst (fp32 from LDS tile)
        const float* av = (t < 128 ? a_src : a_dst) + head * OUT_DIM;
        const int tt = t & 127;
        const int row = tt >> 2, part = tt & 3;
        float s = 0.f;
#pragma unroll
        for (int n2 = 0; n2 < 16; ++n2) s += hs[row][part * 16 + n2] * av[part * 16 + n2];
        s += __shfl_xor(s, 1, 64);
        s += __shfl_xor(s, 2, 64);
        if (part == 0) {
            float* dst = (t < 128 ? fsrc : fdst);
            dst[head * N_NODES + m0 + row] = s;
        }
    }
    __threadfence();
    cg::this_grid().sync();

    // ---------------- Phase C: edge softmax + aggregate ----------------
    for (int i = b; i < N_NODES; i += NBLK) {
        if (t == 0) s_cnt = 0;
        __syncthreads();   // also fences prior iteration's s_idx/s_p reads

        const float4* arow4 = (const float4*)(adj + (size_t)i * N_NODES);
#pragma unroll
        for (int it = 0; it < 3; ++it) {
            const int jj = t + it * 256;        // 768 float4 = 3072 cols
            float4 v = arow4[jj];
            const int j = jj * 4;
            if (v.x > 0.f) { int s = atomicAdd(&s_cnt, 1); if (s < MAX_E) s_idx[s] = j; }
            if (v.y > 0.f) { int s = atomicAdd(&s_cnt, 1); if (s < MAX_E) s_idx[s] = j + 1; }
            if (v.z > 0.f) { int s = atomicAdd(&s_cnt, 1); if (s < MAX_E) s_idx[s] = j + 2; }
            if (v.w > 0.f) { int s = atomicAdd(&s_cnt, 1); if (s < MAX_E) s_idx[s] = j + 3; }
        }
        __syncthreads();
        const int E = min(s_cnt, MAX_E);        // self-loop -> E >= 1

        const int half = lane >> 5;             // 0 or 1
        const int sl = lane & 31;               // sub-lane within half
        const int head = 2 * w + half;          // wave w covers heads {2w, 2w+1}

        const float fi = fsrc[head * N_NODES + i];

        // pass 1: logits + half-wave max
        float m = -1e30f;
        for (int k = sl; k < E; k += 32) {
            float e = fi + fdst[head * N_NODES + s_idx[k]];
            e = e > 0.f ? e : NEG_SLOPE * e;
            s_p[head][k] = e;
            m = fmaxf(m, e);
        }
#pragma unroll
        for (int o = 16; o; o >>= 1) m = fmaxf(m, __shfl_xor(m, o, 64));

        // pass 2: exp + half-wave sum
        float sum = 0.f;
        for (int k = sl; k < E; k += 32) {
            float p = __expf(s_p[head][k] - m);
            s_p[head][k] = p;
            sum += p;
        }
#pragma unroll
        for (int o = 16; o; o >>= 1) sum += __shfl_xor(sum, o, 64);
        const float inv = 1.f / sum;

        __syncthreads();   // fence striped s_p writes before all-k reads

        // gather-aggregate: lane owns dims {sl*2, sl*2+1} of its head.
        // One dword (bf16 pair) per lane per edge; wave covers 256B contiguous.
        const unsigned short* hbase = hb + head * OUT_DIM + sl * 2;
        float a0 = 0.f, a1 = 0.f;
#pragma unroll 8
        for (int k = 0; k < E; ++k) {
            const int j = s_idx[k];
            const float p = s_p[head][k];
            const unsigned u = *(const unsigned*)(hbase + (size_t)j * (HEADS * OUT_DIM));
            a0 = fmaf(p, __uint_as_float(u << 16), a0);
            a1 = fmaf(p, __uint_as_float(u & 0xffff0000u), a1);
        }
        float2 r2 = {a0 * inv, a1 * inv};
        *(float2*)(out + (size_t)i * (HEADS * OUT_DIM) + head * OUT_DIM + sl * 2) = r2;
    }
}

extern "C" void kernel_launch(void* const* d_in, const int* in_sizes, int n_in,
                              void* d_out, int out_size, void* d_ws, size_t ws_size,
                              hipStream_t stream) {
    const float* x     = (const float*)d_in[0];
    const float* adj   = (const float*)d_in[1];
    const float* W     = (const float*)d_in[2];
    const float* a_src = (const float*)d_in[3];
    const float* a_dst = (const float*)d_in[4];
    float* out = (float*)d_out;

    float* fsrc = (float*)d_ws;                               // [H,N]
    float* fdst = fsrc + HEADS * N_NODES;                     // [H,N]
    unsigned short* hb = (unsigned short*)(fdst + HEADS * N_NODES);   // [N, H*64] bf16
    short* xfrag = (short*)(hb + (size_t)N_NODES * HEADS * OUT_DIM);
    short* wfrag = xfrag + (size_t)XFRAG_TILES * KTILES * 64 * 8;

    void* args[] = {(void*)&x, (void*)&adj, (void*)&W, (void*)&a_src, (void*)&a_dst,
                    (void*)&xfrag, (void*)&wfrag, (void*)&hb, (void*)&fsrc,
                    (void*)&fdst, (void*)&out};
    hipLaunchCooperativeKernel((const void*)gat_fused, dim3(NBLK), dim3(256),
                               args, 0, stream);
}

// Round 2
// 144.384 us; speedup vs baseline: 2.5665x; 2.5665x over previous
//
#include <hip/hip_runtime.h>

#define N_NODES 3072
#define IN_DIM 512
#define OUT_DIM 64
#define HEADS 8
#define NEG_SLOPE 0.2f
#define MAX_E 128            // Poisson(~31) edges/row; 128 is >17 sigma
#define KTILES (IN_DIM / 32) // 16 k-tiles

typedef __attribute__((ext_vector_type(8))) short bf16x8;
typedef __attribute__((ext_vector_type(4))) float f32x4;

__device__ inline unsigned short f2bf(float f) {   // RNE float->bf16
    union { float f; unsigned u; } v; v.f = f;
    unsigned r = (v.u + 0x7FFF + ((v.u >> 16) & 1)) >> 16;
    return (unsigned short)r;
}

// Kernel 1: h[head] = x @ W[head] with fragment construction fused in
// (no prep kernel, no fragment buffers, no grid sync).
// Block = 4 waves = 32 rows x 64 cols, one head. Wave w owns col-slice
// w*16..w*16+15; its B-fragments (W slice, bf16) live in 64 VGPRs, gathered
// from fp32 W once per block (W = 1 MB fp32 -> L2-resident; re-reads cheap).
// A-fragments are loaded as 2x float4 straight from x and converted inline
// (32 B contiguous per lane). Grid (rtp, head): head*96+rtp = linear id keeps
// all 8 heads of a row-tile group on one XCD (96 % 8 == 0) -> x L2-shared.
// Epilogue writes h as bf16 NODE-MAJOR hb[n][head*64+col] (L2-resident 3.1 MB
// for the agg gather) + fp32 f_src/f_dst via LDS tile.
__global__ __launch_bounds__(256, 3) void gat_proj(
    const float* __restrict__ x, const float* __restrict__ W,
    const float* __restrict__ a_src, const float* __restrict__ a_dst,
    unsigned short* __restrict__ hb, float* __restrict__ fsrc,
    float* __restrict__ fdst) {
    __shared__ float hs[32][OUT_DIM + 1];

    const int t = threadIdx.x;
    const int lane = t & 63;
    const int w = t >> 6;
    const int head = blockIdx.y;
    const int m0 = blockIdx.x * 32;

    const int colr = lane & 15;      // fragment minor index
    const int kq = lane >> 4;        // 0..3: k-quarter within 32-wide k-tile

    // ---- B-operand fragments: W[head][kt*32 + kq*8 + j][w*16 + colr] ----
    bf16x8 wf[KTILES];
    {
        const float* wp0 = W + ((size_t)head * IN_DIM + kq * 8) * OUT_DIM + w * 16 + colr;
#pragma unroll
        for (int kt = 0; kt < KTILES; ++kt) {
            const float* wp = wp0 + (size_t)kt * 32 * OUT_DIM;
            bf16x8 r;
#pragma unroll
            for (int j = 0; j < 8; ++j) r[j] = (short)f2bf(wp[(size_t)j * OUT_DIM]);
            wf[kt] = r;
        }
    }

    // ---- A-operand: rows m0+colr and m0+16+colr, cols kt*32 + kq*8 .. +7 ----
    const float* xr0 = x + (size_t)(m0 + colr) * IN_DIM + kq * 8;
    const float* xr1 = xr0 + (size_t)16 * IN_DIM;

    f32x4 acc0 = {0.f, 0.f, 0.f, 0.f};
    f32x4 acc1 = {0.f, 0.f, 0.f, 0.f};
#pragma unroll 2
    for (int kt = 0; kt < KTILES; ++kt) {
        const float4* p0 = (const float4*)(xr0 + kt * 32);
        const float4* p1 = (const float4*)(xr1 + kt * 32);
        float4 u0 = p0[0], u1 = p0[1];
        float4 v0 = p1[0], v1 = p1[1];
        bf16x8 a0, a1;
        a0[0] = (short)f2bf(u0.x); a0[1] = (short)f2bf(u0.y);
        a0[2] = (short)f2bf(u0.z); a0[3] = (short)f2bf(u0.w);
        a0[4] = (short)f2bf(u1.x); a0[5] = (short)f2bf(u1.y);
        a0[6] = (short)f2bf(u1.z); a0[7] = (short)f2bf(u1.w);
        a1[0] = (short)f2bf(v0.x); a1[1] = (short)f2bf(v0.y);
        a1[2] = (short)f2bf(v0.z); a1[3] = (short)f2bf(v0.w);
        a1[4] = (short)f2bf(v1.x); a1[5] = (short)f2bf(v1.y);
        a1[6] = (short)f2bf(v1.z); a1[7] = (short)f2bf(v1.w);
        acc0 = __builtin_amdgcn_mfma_f32_16x16x32_bf16(a0, wf[kt], acc0, 0, 0, 0);
        acc1 = __builtin_amdgcn_mfma_f32_16x16x32_bf16(a1, wf[kt], acc1, 0, 0, 0);
    }

    // D mapping: col=lane&15 (within tile), row=(lane>>4)*4+i
    const int col = w * 16 + colr;
    const int r0 = kq * 4;
    unsigned short* hp = hb + (size_t)m0 * (HEADS * OUT_DIM) + head * OUT_DIM + col;
#pragma unroll
    for (int i2 = 0; i2 < 4; ++i2) {
        hs[r0 + i2][col] = acc0[i2];
        hs[r0 + 16 + i2][col] = acc1[i2];
        hp[(size_t)(r0 + i2) * (HEADS * OUT_DIM)] = f2bf(acc0[i2]);
        hp[(size_t)(r0 + 16 + i2) * (HEADS * OUT_DIM)] = f2bf(acc1[i2]);
    }
    __syncthreads();

    // f-pass: threads 0..127 -> f_src, 128..255 -> f_dst (fp32 from LDS tile)
    {
        const float* av = (t < 128 ? a_src : a_dst) + head * OUT_DIM;
        const int tt = t & 127;
        const int row = tt >> 2, part = tt & 3;
        float s = 0.f;
#pragma unroll
        for (int n = 0; n < 16; ++n) s += hs[row][part * 16 + n] * av[part * 16 + n];
        s += __shfl_xor(s, 1, 64);
        s += __shfl_xor(s, 2, 64);
        if (part == 0) {
            float* dst = (t < 128 ? fsrc : fdst);
            dst[head * N_NODES + m0 + row] = s;
        }
    }
}

// Kernel 2: one block per row i. Compact edge list, then wave w handles heads
// {2w, 2w+1}: lanes 0..31 -> head 2w, lanes 32..63 -> head 2w+1, each lane
// owning 2 output dims. Gather = ONE coalesced 256B dword load per wave per
// edge (bf16 pairs, node-major hb), covering both heads. Half-wave softmax.
// NOTE: __syncthreads() between softmax (striped s_p writes) and gather
// (all-k s_p reads) — cross-lane LDS dependency must be fenced.
__global__ __launch_bounds__(256) void gat_agg(
    const float* __restrict__ adj, const unsigned short* __restrict__ hb,
    const float* __restrict__ fsrc, const float* __restrict__ fdst,
    float* __restrict__ out) {
    __shared__ int s_idx[MAX_E];
    __shared__ float s_p[HEADS][MAX_E];
    __shared__ int s_cnt;

    const int i = blockIdx.x;
    const int t = threadIdx.x;
    if (t == 0) s_cnt = 0;
    __syncthreads();

    const float4* arow4 = (const float4*)(adj + (size_t)i * N_NODES);
#pragma unroll
    for (int it = 0; it < 3; ++it) {
        const int jj = t + it * 256;            // 768 float4 = 3072 cols
        float4 v = arow4[jj];
        const int j = jj * 4;
        if (v.x > 0.f) { int s = atomicAdd(&s_cnt, 1); if (s < MAX_E) s_idx[s] = j; }
        if (v.y > 0.f) { int s = atomicAdd(&s_cnt, 1); if (s < MAX_E) s_idx[s] = j + 1; }
        if (v.z > 0.f) { int s = atomicAdd(&s_cnt, 1); if (s < MAX_E) s_idx[s] = j + 2; }
        if (v.w > 0.f) { int s = atomicAdd(&s_cnt, 1); if (s < MAX_E) s_idx[s] = j + 3; }
    }
    __syncthreads();
    const int E = min(s_cnt, MAX_E);            // self-loop -> E >= 1

    const int w = t >> 6;
    const int lane = t & 63;
    const int half = lane >> 5;                 // 0 or 1
    const int sl = lane & 31;                   // sub-lane within half
    const int head = 2 * w + half;

    const float fi = fsrc[head * N_NODES + i];

    // pass 1: logits + half-wave max
    float m = -1e30f;
    for (int k = sl; k < E; k += 32) {
        float e = fi + fdst[head * N_NODES + s_idx[k]];
        e = e > 0.f ? e : NEG_SLOPE * e;
        s_p[head][k] = e;
        m = fmaxf(m, e);
    }
#pragma unroll
    for (int o = 16; o; o >>= 1) m = fmaxf(m, __shfl_xor(m, o, 64));

    // pass 2: exp + half-wave sum
    float sum = 0.f;
    for (int k = sl; k < E; k += 32) {
        float p = __expf(s_p[head][k] - m);
        s_p[head][k] = p;
        sum += p;
    }
#pragma unroll
    for (int o = 16; o; o >>= 1) sum += __shfl_xor(sum, o, 64);
    const float inv = 1.f / sum;

    __syncthreads();   // fence striped s_p writes before all-k reads

    // gather-aggregate: lane owns dims {sl*2, sl*2+1} of its head.
    // One dword (bf16 pair) per lane per edge; wave covers 256B contiguous.
    const unsigned short* hbase = hb + head * OUT_DIM + sl * 2;
    float a0 = 0.f, a1 = 0.f;
#pragma unroll 8
    for (int k = 0; k < E; ++k) {
        const int j = s_idx[k];
        const float p = s_p[head][k];
        const unsigned u = *(const unsigned*)(hbase + (size_t)j * (HEADS * OUT_DIM));
        a0 = fmaf(p, __uint_as_float(u << 16), a0);
        a1 = fmaf(p, __uint_as_float(u & 0xffff0000u), a1);
    }
    float2 r = {a0 * inv, a1 * inv};
    *(float2*)(out + (size_t)i * (HEADS * OUT_DIM) + head * OUT_DIM + sl * 2) = r;
}

extern "C" void kernel_launch(void* const* d_in, const int* in_sizes, int n_in,
                              void* d_out, int out_size, void* d_ws, size_t ws_size,
                              hipStream_t stream) {
    const float* x     = (const float*)d_in[0];
    const float* adj   = (const float*)d_in[1];
    const float* W     = (const float*)d_in[2];
    const float* a_src = (const float*)d_in[3];
    const float* a_dst = (const float*)d_in[4];
    float* out = (float*)d_out;

    float* fsrc = (float*)d_ws;                               // [H,N]
    float* fdst = fsrc + HEADS * N_NODES;                     // [H,N]
    unsigned short* hb = (unsigned short*)(fdst + HEADS * N_NODES);   // [N, H*64] bf16

    gat_proj<<<dim3(N_NODES / 32, HEADS), 256, 0, stream>>>(
        x, W, a_src, a_dst, hb, fsrc, fdst);
    gat_agg<<<N_NODES, 256, 0, stream>>>(adj, hb, fsrc, fdst, out);
}

// Round 3
// 124.064 us; speedup vs baseline: 2.9868x; 1.1638x over previous
//
#include <hip/hip_runtime.h>

#define N_NODES 3072
#define IN_DIM 512
#define OUT_DIM 64
#define HEADS 8
#define NEG_SLOPE 0.2f
#define MAX_E 128            // Poisson(~31) edges/row; 128 is >17 sigma
#define KTILES (IN_DIM / 32) // 16 k-tiles

typedef __attribute__((ext_vector_type(8))) short bf16x8;
typedef __attribute__((ext_vector_type(4))) float f32x4;

__device__ inline unsigned short f2bf(float f) {   // RNE float->bf16
    union { float f; unsigned u; } v; v.f = f;
    unsigned r = (v.u + 0x7FFF + ((v.u >> 16) & 1)) >> 16;
    return (unsigned short)r;
}

// Kernel 1: h[head] = x @ W[head] with fragment construction fused in
// (no prep kernel, no fragment buffers). Block = 4 waves = 32 rows x 64 cols,
// one head. Wave w owns col-slice w*16..w*16+15.
// CRITICAL (rule #20 post-mortem, R2): the k-loop is FULLY unrolled and the
// B-fragment is built inline per iteration — no bf16x8 array with a runtime
// index exists, so nothing is demoted to scratch. (R2's `wf[kt]` under
// `#pragma unroll 2` spilled 64 VGPRs -> 49 MB of scratch writes, 48.8 us.)
// Grid dim3(96, 8): linear id = rtp + head*96, 96 % 8 == 0, so all 8 heads of
// a row-tile group land on the SAME XCD -> x-tile read once into that L2 and
// shared by the 8 head-blocks. W (1 MB fp32) is L2-resident everywhere.
// Epilogue writes h as bf16 NODE-MAJOR hb[n][head*64+col] (L2-resident 3.1 MB
// for the agg gather) + fp32 f_src/f_dst via LDS tile.
__global__ __launch_bounds__(256, 3) void gat_proj(
    const float* __restrict__ x, const float* __restrict__ W,
    const float* __restrict__ a_src, const float* __restrict__ a_dst,
    unsigned short* __restrict__ hb, float* __restrict__ fsrc,
    float* __restrict__ fdst) {
    __shared__ float hs[32][OUT_DIM + 1];

    const int t = threadIdx.x;
    const int lane = t & 63;
    const int w = t >> 6;
    const int head = blockIdx.y;
    const int m0 = blockIdx.x * 32;

    const int colr = lane & 15;      // fragment minor index
    const int kq = lane >> 4;        // 0..3: k-quarter within 32-wide k-tile

    // B-operand base: W[head][kt*32 + kq*8 + j][w*16 + colr]
    const float* wp0 = W + ((size_t)head * IN_DIM + kq * 8) * OUT_DIM + w * 16 + colr;
    // A-operand: rows m0+colr and m0+16+colr, cols kt*32 + kq*8 .. +7
    const float* xr0 = x + (size_t)(m0 + colr) * IN_DIM + kq * 8;
    const float* xr1 = xr0 + (size_t)16 * IN_DIM;

    f32x4 acc0 = {0.f, 0.f, 0.f, 0.f};
    f32x4 acc1 = {0.f, 0.f, 0.f, 0.f};
#pragma unroll
    for (int kt = 0; kt < KTILES; ++kt) {   // FULL unroll: all indices static
        const float* wp = wp0 + (size_t)kt * 32 * OUT_DIM;
        bf16x8 bv;
#pragma unroll
        for (int j = 0; j < 8; ++j) bv[j] = (short)f2bf(wp[(size_t)j * OUT_DIM]);

        const float4* p0 = (const float4*)(xr0 + kt * 32);
        const float4* p1 = (const float4*)(xr1 + kt * 32);
        float4 u0 = p0[0], u1 = p0[1];
        float4 v0 = p1[0], v1 = p1[1];
        bf16x8 a0, a1;
        a0[0] = (short)f2bf(u0.x); a0[1] = (short)f2bf(u0.y);
        a0[2] = (short)f2bf(u0.z); a0[3] = (short)f2bf(u0.w);
        a0[4] = (short)f2bf(u1.x); a0[5] = (short)f2bf(u1.y);
        a0[6] = (short)f2bf(u1.z); a0[7] = (short)f2bf(u1.w);
        a1[0] = (short)f2bf(v0.x); a1[1] = (short)f2bf(v0.y);
        a1[2] = (short)f2bf(v0.z); a1[3] = (short)f2bf(v0.w);
        a1[4] = (short)f2bf(v1.x); a1[5] = (short)f2bf(v1.y);
        a1[6] = (short)f2bf(v1.z); a1[7] = (short)f2bf(v1.w);
        acc0 = __builtin_amdgcn_mfma_f32_16x16x32_bf16(a0, bv, acc0, 0, 0, 0);
        acc1 = __builtin_amdgcn_mfma_f32_16x16x32_bf16(a1, bv, acc1, 0, 0, 0);
    }

    // D mapping: col=lane&15 (within tile), row=(lane>>4)*4+i
    const int col = w * 16 + colr;
    const int r0 = kq * 4;
    unsigned short* hp = hb + (size_t)m0 * (HEADS * OUT_DIM) + head * OUT_DIM + col;
#pragma unroll
    for (int i2 = 0; i2 < 4; ++i2) {
        hs[r0 + i2][col] = acc0[i2];
        hs[r0 + 16 + i2][col] = acc1[i2];
        hp[(size_t)(r0 + i2) * (HEADS * OUT_DIM)] = f2bf(acc0[i2]);
        hp[(size_t)(r0 + 16 + i2) * (HEADS * OUT_DIM)] = f2bf(acc1[i2]);
    }
    __syncthreads();

    // f-pass: threads 0..127 -> f_src, 128..255 -> f_dst (fp32 from LDS tile)
    {
        const float* av = (t < 128 ? a_src : a_dst) + head * OUT_DIM;
        const int tt = t & 127;
        const int row = tt >> 2, part = tt & 3;
        float s = 0.f;
#pragma unroll
        for (int n = 0; n < 16; ++n) s += hs[row][part * 16 + n] * av[part * 16 + n];
        s += __shfl_xor(s, 1, 64);
        s += __shfl_xor(s, 2, 64);
        if (part == 0) {
            float* dst = (t < 128 ? fsrc : fdst);
            dst[head * N_NODES + m0 + row] = s;
        }
    }
}

// Kernel 2: one block per row i. Compact edge list, then wave w handles heads
// {2w, 2w+1}: lanes 0..31 -> head 2w, lanes 32..63 -> head 2w+1, each lane
// owning 2 output dims. Gather = ONE coalesced 256B dword load per wave per
// edge (bf16 pairs, node-major hb), covering both heads. Half-wave softmax.
// NOTE: __syncthreads() between softmax (striped s_p writes) and gather
// (all-k s_p reads) — cross-lane LDS dependency must be fenced.
__global__ __launch_bounds__(256) void gat_agg(
    const float* __restrict__ adj, const unsigned short* __restrict__ hb,
    const float* __restrict__ fsrc, const float* __restrict__ fdst,
    float* __restrict__ out) {
    __shared__ int s_idx[MAX_E];
    __shared__ float s_p[HEADS][MAX_E];
    __shared__ int s_cnt;

    const int i = blockIdx.x;
    const int t = threadIdx.x;
    if (t == 0) s_cnt = 0;
    __syncthreads();

    const float4* arow4 = (const float4*)(adj + (size_t)i * N_NODES);
#pragma unroll
    for (int it = 0; it < 3; ++it) {
        const int jj = t + it * 256;            // 768 float4 = 3072 cols
        float4 v = arow4[jj];
        const int j = jj * 4;
        if (v.x > 0.f) { int s = atomicAdd(&s_cnt, 1); if (s < MAX_E) s_idx[s] = j; }
        if (v.y > 0.f) { int s = atomicAdd(&s_cnt, 1); if (s < MAX_E) s_idx[s] = j + 1; }
        if (v.z > 0.f) { int s = atomicAdd(&s_cnt, 1); if (s < MAX_E) s_idx[s] = j + 2; }
        if (v.w > 0.f) { int s = atomicAdd(&s_cnt, 1); if (s < MAX_E) s_idx[s] = j + 3; }
    }
    __syncthreads();
    const int E = min(s_cnt, MAX_E);            // self-loop -> E >= 1

    const int w = t >> 6;
    const int lane = t & 63;
    const int half = lane >> 5;                 // 0 or 1
    const int sl = lane & 31;                   // sub-lane within half
    const int head = 2 * w + half;

    const float fi = fsrc[head * N_NODES + i];

    // pass 1: logits + half-wave max
    float m = -1e30f;
    for (int k = sl; k < E; k += 32) {
        float e = fi + fdst[head * N_NODES + s_idx[k]];
        e = e > 0.f ? e : NEG_SLOPE * e;
        s_p[head][k] = e;
        m = fmaxf(m, e);
    }
#pragma unroll
    for (int o = 16; o; o >>= 1) m = fmaxf(m, __shfl_xor(m, o, 64));

    // pass 2: exp + half-wave sum
    float sum = 0.f;
    for (int k = sl; k < E; k += 32) {
        float p = __expf(s_p[head][k] - m);
        s_p[head][k] = p;
        sum += p;
    }
#pragma unroll
    for (int o = 16; o; o >>= 1) sum += __shfl_xor(sum, o, 64);
    const float inv = 1.f / sum;

    __syncthreads();   // fence striped s_p writes before all-k reads

    // gather-aggregate: lane owns dims {sl*2, sl*2+1} of its head.
    // One dword (bf16 pair) per lane per edge; wave covers 256B contiguous.
    const unsigned short* hbase = hb + head * OUT_DIM + sl * 2;
    float a0 = 0.f, a1 = 0.f;
#pragma unroll 8
    for (int k = 0; k < E; ++k) {
        const int j = s_idx[k];
        const float p = s_p[head][k];
        const unsigned u = *(const unsigned*)(hbase + (size_t)j * (HEADS * OUT_DIM));
        a0 = fmaf(p, __uint_as_float(u << 16), a0);
        a1 = fmaf(p, __uint_as_float(u & 0xffff0000u), a1);
    }
    float2 r = {a0 * inv, a1 * inv};
    *(float2*)(out + (size_t)i * (HEADS * OUT_DIM) + head * OUT_DIM + sl * 2) = r;
}

extern "C" void kernel_launch(void* const* d_in, const int* in_sizes, int n_in,
                              void* d_out, int out_size, void* d_ws, size_t ws_size,
                              hipStream_t stream) {
    const float* x     = (const float*)d_in[0];
    const float* adj   = (const float*)d_in[1];
    const float* W     = (const float*)d_in[2];
    const float* a_src = (const float*)d_in[3];
    const float* a_dst = (const float*)d_in[4];
    float* out = (float*)d_out;

    float* fsrc = (float*)d_ws;                               // [H,N]
    float* fdst = fsrc + HEADS * N_NODES;                     // [H,N]
    unsigned short* hb = (unsigned short*)(fdst + HEADS * N_NODES);   // [N, H*64] bf16

    gat_proj<<<dim3(N_NODES / 32, HEADS), 256, 0, stream>>>(
        x, W, a_src, a_dst, hb, fsrc, fdst);
    gat_agg<<<N_NODES, 256, 0, stream>>>(adj, hb, fsrc, fdst, out);
}

// Round 4
// 108.100 us; speedup vs baseline: 3.4279x; 1.1477x over previous
//
#include <hip/hip_runtime.h>

#define N_NODES 3072
#define IN_DIM 512
#define OUT_DIM 64
#define HEADS 8
#define NEG_SLOPE 0.2f
#define MAX_E 128            // Poisson(~31) edges/row; 128 is >17 sigma

typedef __attribute__((ext_vector_type(8))) short bf16x8;
typedef __attribute__((ext_vector_type(4))) float f32x4;

#define XFRAG_TILES (N_NODES / 16)     // 192 row-tiles
#define KTILES (IN_DIM / 32)           // 16 k-tiles
#define XFRAG_THREADS (XFRAG_TILES * KTILES * 64)   // 196608
#define WFRAG_THREADS (HEADS * KTILES * 4 * 64)     // 32768
#define PROJ_BLOCKS (N_NODES / 32 * HEADS)          // 768

__device__ inline unsigned short f2bf(float f) {   // RNE float->bf16
    union { float f; unsigned u; } v; v.f = f;
    unsigned r = (v.u + 0x7FFF + ((v.u >> 16) & 1)) >> 16;
    return (unsigned short)r;
}

// Kernel 0: build bf16 fragment-ready copies of x and W (R0 known-good).
// xfrag[rt][kt][lane][8]: lane l holds x[rt*16 + (l&15)][kt*32 + (l>>4)*8 + j]
// wfrag[head][kt][c][lane][8]: lane l holds W[head][kt*32+(l>>4)*8+j][c*16+(l&15)]
__global__ __launch_bounds__(256) void gat_prep(
    const float* __restrict__ x, const float* __restrict__ W,
    short* __restrict__ xfrag, short* __restrict__ wfrag) {
    int tid = blockIdx.x * 256 + threadIdx.x;
    if (tid < XFRAG_THREADS) {
        int lane = tid & 63;
        int kt = (tid >> 6) & (KTILES - 1);
        int rt = tid >> 10;
        int m = rt * 16 + (lane & 15);
        int k0 = kt * 32 + (lane >> 4) * 8;
        const float4* xp = (const float4*)(x + (size_t)m * IN_DIM + k0);
        float4 v0 = xp[0], v1 = xp[1];
        bf16x8 r;
        r[0] = (short)f2bf(v0.x); r[1] = (short)f2bf(v0.y);
        r[2] = (short)f2bf(v0.z); r[3] = (short)f2bf(v0.w);
        r[4] = (short)f2bf(v1.x); r[5] = (short)f2bf(v1.y);
        r[6] = (short)f2bf(v1.z); r[7] = (short)f2bf(v1.w);
        ((bf16x8*)xfrag)[tid] = r;
    } else {
        int t2 = tid - XFRAG_THREADS;
        if (t2 >= WFRAG_THREADS) return;
        int lane = t2 & 63;
        int c = (t2 >> 6) & 3;
        int kt = (t2 >> 8) & (KTILES - 1);
        int head = t2 >> 12;
        int n = c * 16 + (lane & 15);
        int k0 = kt * 32 + (lane >> 4) * 8;
        const float* wp = W + ((size_t)head * IN_DIM + k0) * OUT_DIM + n;
        bf16x8 r;
#pragma unroll
        for (int j = 0; j < 8; ++j) r[j] = (short)f2bf(wp[(size_t)j * OUT_DIM]);
        ((bf16x8*)wfrag)[t2] = r;
    }
}

// Kernel 1: blocks 0..767 = projection (R0 known-good proj); blocks 768..3839
// = adj edge-compaction, one row each, writing compacted lists to workspace.
// The scan is HBM-BW-bound (37.7 MB) and independent of proj's output; proj
// is latency/L2-bound — co-dispatching lets the scan stream HBM underneath
// proj's MFMA/L2 work instead of serializing after it.
__global__ __launch_bounds__(256) void gat_proj_scan(
    const short* __restrict__ xfrag, const short* __restrict__ wfrag,
    const float* __restrict__ a_src, const float* __restrict__ a_dst,
    const float* __restrict__ adj,
    unsigned short* __restrict__ hb, float* __restrict__ fsrc,
    float* __restrict__ fdst, int* __restrict__ e_idx, int* __restrict__ e_cnt) {
    __shared__ float hs[32][OUT_DIM + 1];   // proj epilogue
    __shared__ int s_idx[MAX_E];            // scan
    __shared__ int s_cnt;                   // scan

    const int b = blockIdx.x;
    const int t = threadIdx.x;

    if (b < PROJ_BLOCKS) {
        // ---- projection: head = b/96, row-pair tile rtp = b%96 (same linear
        // dispatch order as R0's dim3(96,8) -> 8 heads of a tile share an XCD)
        const int lane = t & 63;
        const int w = t >> 6;
        const int head = b / 96;
        const int rtp = b % 96;
        const int m0 = rtp * 32;
        const int rt0 = rtp * 2;

        const bf16x8* xa = (const bf16x8*)xfrag + (size_t)rt0 * 16 * 64 + lane;
        const bf16x8* wb = (const bf16x8*)wfrag + ((size_t)head * KTILES * 4 + w) * 64 + lane;

        f32x4 acc0 = {0.f, 0.f, 0.f, 0.f};
        f32x4 acc1 = {0.f, 0.f, 0.f, 0.f};
#pragma unroll
        for (int kt = 0; kt < KTILES; ++kt) {
            bf16x8 a0 = xa[kt * 64];            // rows m0..m0+15
            bf16x8 a1 = xa[(16 + kt) * 64];     // rows m0+16..m0+31
            bf16x8 bv = wb[kt * 4 * 64];        // cols w*16..w*16+15
            acc0 = __builtin_amdgcn_mfma_f32_16x16x32_bf16(a0, bv, acc0, 0, 0, 0);
            acc1 = __builtin_amdgcn_mfma_f32_16x16x32_bf16(a1, bv, acc1, 0, 0, 0);
        }

        // D mapping: col=lane&15 (within tile), row=(lane>>4)*4+i
        const int col = w * 16 + (lane & 15);
        const int r0 = (lane >> 4) * 4;
        unsigned short* hp = hb + (size_t)m0 * (HEADS * OUT_DIM) + head * OUT_DIM + col;
#pragma unroll
        for (int i2 = 0; i2 < 4; ++i2) {
            hs[r0 + i2][col] = acc0[i2];
            hs[r0 + 16 + i2][col] = acc1[i2];
            hp[(size_t)(r0 + i2) * (HEADS * OUT_DIM)] = f2bf(acc0[i2]);
            hp[(size_t)(r0 + 16 + i2) * (HEADS * OUT_DIM)] = f2bf(acc1[i2]);
        }
        __syncthreads();

        // f-pass: threads 0..127 -> f_src, 128..255 -> f_dst (fp32 LDS tile)
        const float* av = (t < 128 ? a_src : a_dst) + head * OUT_DIM;
        const int tt = t & 127;
        const int row = tt >> 2, part = tt & 3;
        float s = 0.f;
#pragma unroll
        for (int n = 0; n < 16; ++n) s += hs[row][part * 16 + n] * av[part * 16 + n];
        s += __shfl_xor(s, 1, 64);
        s += __shfl_xor(s, 2, 64);
        if (part == 0) {
            float* dst = (t < 128 ? fsrc : fdst);
            dst[head * N_NODES + m0 + row] = s;
        }
    } else {
        // ---- edge compaction for row i: find nonzeros, write packed list
        const int i = b - PROJ_BLOCKS;
        if (t == 0) s_cnt = 0;
        __syncthreads();

        const float4* arow4 = (const float4*)(adj + (size_t)i * N_NODES);
#pragma unroll
        for (int it = 0; it < 3; ++it) {
            const int jj = t + it * 256;        // 768 float4 = 3072 cols
            float4 v = arow4[jj];
            const int j = jj * 4;
            if (v.x > 0.f) { int s = atomicAdd(&s_cnt, 1); if (s < MAX_E) s_idx[s] = j; }
            if (v.y > 0.f) { int s = atomicAdd(&s_cnt, 1); if (s < MAX_E) s_idx[s] = j + 1; }
            if (v.z > 0.f) { int s = atomicAdd(&s_cnt, 1); if (s < MAX_E) s_idx[s] = j + 2; }
            if (v.w > 0.f) { int s = atomicAdd(&s_cnt, 1); if (s < MAX_E) s_idx[s] = j + 3; }
        }
        __syncthreads();
        const int E = min(s_cnt, MAX_E);        // self-loop -> E >= 1
        if (t < E) e_idx[(size_t)i * MAX_E + t] = s_idx[t];
        if (t == 0) e_cnt[i] = E;
    }
}

// Kernel 2: softmax + gather-aggregate from precompacted edge lists.
// One block per row i. Wave w handles heads {2w, 2w+1}: lanes 0..31 -> head
// 2w, lanes 32..63 -> head 2w+1, each lane owning 2 output dims. Gather =
// ONE coalesced 256B dword load per wave per edge (bf16 pairs, node-major hb).
__global__ __launch_bounds__(256) void gat_agg(
    const int* __restrict__ e_idx, const int* __restrict__ e_cnt,
    const unsigned short* __restrict__ hb,
    const float* __restrict__ fsrc, const float* __restrict__ fdst,
    float* __restrict__ out) {
    __shared__ int s_idx[MAX_E];
    __shared__ float s_p[HEADS][MAX_E];

    const int i = blockIdx.x;
    const int t = threadIdx.x;
    const int E = e_cnt[i];                     // uniform scalar load
    if (t < E) s_idx[t] = e_idx[(size_t)i * MAX_E + t];
    __syncthreads();

    const int w = t >> 6;
    const int lane = t & 63;
    const int half = lane >> 5;                 // 0 or 1
    const int sl = lane & 31;                   // sub-lane within half
    const int head = 2 * w + half;

    const float fi = fsrc[head * N_NODES + i];

    // pass 1: logits + half-wave max
    float m = -1e30f;
    for (int k = sl; k < E; k += 32) {
        float e = fi + fdst[head * N_NODES + s_idx[k]];
        e = e > 0.f ? e : NEG_SLOPE * e;
        s_p[head][k] = e;
        m = fmaxf(m, e);
    }
#pragma unroll
    for (int o = 16; o; o >>= 1) m = fmaxf(m, __shfl_xor(m, o, 64));

    // pass 2: exp + half-wave sum
    float sum = 0.f;
    for (int k = sl; k < E; k += 32) {
        float p = __expf(s_p[head][k] - m);
        s_p[head][k] = p;
        sum += p;
    }
#pragma unroll
    for (int o = 16; o; o >>= 1) sum += __shfl_xor(sum, o, 64);
    const float inv = 1.f / sum;

    __syncthreads();   // fence striped s_p writes before all-k reads

    // gather-aggregate: lane owns dims {sl*2, sl*2+1} of its head.
    const unsigned short* hbase = hb + head * OUT_DIM + sl * 2;
    float a0 = 0.f, a1 = 0.f;
#pragma unroll 8
    for (int k = 0; k < E; ++k) {
        const int j = s_idx[k];
        const float p = s_p[head][k];
        const unsigned u = *(const unsigned*)(hbase + (size_t)j * (HEADS * OUT_DIM));
        a0 = fmaf(p, __uint_as_float(u << 16), a0);
        a1 = fmaf(p, __uint_as_float(u & 0xffff0000u), a1);
    }
    float2 r = {a0 * inv, a1 * inv};
    *(float2*)(out + (size_t)i * (HEADS * OUT_DIM) + head * OUT_DIM + sl * 2) = r;
}

extern "C" void kernel_launch(void* const* d_in, const int* in_sizes, int n_in,
                              void* d_out, int out_size, void* d_ws, size_t ws_size,
                              hipStream_t stream) {
    const float* x     = (const float*)d_in[0];
    const float* adj   = (const float*)d_in[1];
    const float* W     = (const float*)d_in[2];
    const float* a_src = (const float*)d_in[3];
    const float* a_dst = (const float*)d_in[4];
    float* out = (float*)d_out;

    float* fsrc = (float*)d_ws;                               // [H,N]
    float* fdst = fsrc + HEADS * N_NODES;                     // [H,N]
    unsigned short* hb = (unsigned short*)(fdst + HEADS * N_NODES);   // [N, H*64] bf16
    short* xfrag = (short*)(hb + (size_t)N_NODES * HEADS * OUT_DIM);
    short* wfrag = xfrag + (size_t)XFRAG_TILES * KTILES * 64 * 8;
    int* e_idx = (int*)(wfrag + (size_t)HEADS * KTILES * 4 * 64 * 8);  // [N, MAX_E]
    int* e_cnt = e_idx + (size_t)N_NODES * MAX_E;                      // [N]

    gat_prep<<<(XFRAG_THREADS + WFRAG_THREADS) / 256, 256, 0, stream>>>(
        x, W, xfrag, wfrag);
    gat_proj_scan<<<PROJ_BLOCKS + N_NODES, 256, 0, stream>>>(
        xfrag, wfrag, a_src, a_dst, adj, hb, fsrc, fdst, e_idx, e_cnt);
    gat_agg<<<N_NODES, 256, 0, stream>>>(e_idx, e_cnt, hb, fsrc, fdst, out);
}